// Round 10
// baseline (2189.774 us; speedup 1.0000x reference)
//
#include <hip/hip_runtime.h>
#include <hip/hip_bf16.h>
#include <math.h>

#define NN 100000
#define NE 800000
#define NG 2048
#define DD 64
#define NR 5
#define KK 384          // 6 * 64 (5 relations + root)
#define NB ((NN + 255) / 256)   // scan blocks = 391
#define CAP 96          // LDS-staged segment rows in k_s2s6

typedef __attribute__((ext_vector_type(8))) short bf16x8;
typedef __attribute__((ext_vector_type(4))) float f32x4;
typedef unsigned short ushort_t;
typedef unsigned int uint_t;

static __device__ __forceinline__ float sigmoidf_(float x) { return 1.0f / (1.0f + expf(-x)); }

static __device__ __forceinline__ ushort_t f2bf(float f) {
    uint_t u = __float_as_uint(f);
    uint_t r = (u + 0x7FFFu + ((u >> 16) & 1u)) >> 16;
    return (ushort_t)r;
}
static __device__ __forceinline__ float bf2f(ushort_t b) {
    return __uint_as_float(((uint_t)b) << 16);
}

// WT[c][k] hi/lo bf16
__global__ void k_w2(const float* __restrict__ att, const float* __restrict__ basis,
                     const float* __restrict__ root, ushort_t* __restrict__ wt_hi,
                     ushort_t* __restrict__ wt_lo) {
    int i = blockIdx.x * blockDim.x + threadIdx.x;
    if (i >= DD * KK) return;
    int c = i / KK;
    int k = i % KK;
    int t = k >> 6;
    int kd = k & 63;
    float w;
    if (t < NR) {
        w = 0.f;
#pragma unroll
        for (int b = 0; b < NR; ++b) w += att[t * NR + b] * basis[(b * DD + kd) * DD + c];
    } else {
        w = root[kd * DD + c];
    }
    ushort_t hi = f2bf(w);
    ushort_t lo = f2bf(w - bf2f(hi));
    wt_hi[c * KK + k] = hi;
    wt_lo[c * KK + k] = lo;
}

// Transposed folded LSTM weights: WqT[c][j] = wih[j,c] + whh[j,c]; WrT[c][j] = wih[j,64+c].
__global__ void k_wf(const float* __restrict__ wih, const float* __restrict__ whh,
                     const float* __restrict__ bih, const float* __restrict__ bhh,
                     float* __restrict__ WqT, float* __restrict__ WrT, float* __restrict__ Wb) {
    int i = blockIdx.x * blockDim.x + threadIdx.x;
    if (i >= 64 * 256) return;
    int c = i >> 8, j = i & 255;
    WqT[i] = wih[j * 128 + c] + whh[j * 64 + c];
    WrT[i] = wih[j * 128 + 64 + c];
    if (c == 0) Wb[j] = bih[j] + bhh[j];
}

__global__ void k_cnt(const int* __restrict__ dst, int* __restrict__ deg) {
    int e = blockIdx.x * blockDim.x + threadIdx.x;
    if (e < NE) atomicAdd(&deg[dst[e]], 1);
}

__global__ void k_scan1(const int* __restrict__ deg, int* __restrict__ part,
                        int* __restrict__ bsum) {
    __shared__ int s[256];
    int tid = threadIdx.x;
    int i = blockIdx.x * 256 + tid;
    int v = (i < NN) ? deg[i] : 0;
    s[tid] = v;
    __syncthreads();
    for (int off = 1; off < 256; off <<= 1) {
        int t = (tid >= off) ? s[tid - off] : 0;
        __syncthreads();
        s[tid] += t;
        __syncthreads();
    }
    if (i < NN) part[i] = s[tid] - v;
    if (tid == 255) bsum[blockIdx.x] = s[255];
}

__global__ void k_scan2(int* __restrict__ bsum) {
    __shared__ int s[512];
    int tid = threadIdx.x;
    int v = (tid < NB) ? bsum[tid] : 0;
    s[tid] = v;
    __syncthreads();
    for (int off = 1; off < 512; off <<= 1) {
        int t = (tid >= off) ? s[tid - off] : 0;
        __syncthreads();
        s[tid] += t;
        __syncthreads();
    }
    if (tid < NB) bsum[tid] = s[tid] - v;
}

__global__ void k_scan3(const int* __restrict__ part, const int* __restrict__ bsum,
                        const int* __restrict__ deg, int* __restrict__ rowptr,
                        float* __restrict__ invc) {
    int i = blockIdx.x * blockDim.x + threadIdx.x;
    if (i >= NN) return;
    rowptr[i] = part[i] + bsum[i >> 8];
    invc[i] = 1.0f / fmaxf((float)deg[i], 1.0f);
    if (i == 0) rowptr[NN] = NE;
}

// fill CSR: eidx[pos] = src | type<<20 | (dst&31)<<23  (blocks are 32-aligned)
__global__ void k_fill(const int* __restrict__ src, const int* __restrict__ dst,
                       const int* __restrict__ et, int* __restrict__ cur,
                       int* __restrict__ eidx) {
    int e = blockIdx.x * blockDim.x + threadIdx.x;
    if (e >= NE) return;
    int d = dst[e];
    int pos = atomicAdd(&cur[d], 1);
    eidx[pos] = src[e] | (et[e] << 20) | ((d & 31) << 23);
}

__global__ void k_seg(const int* __restrict__ batch, int* __restrict__ seg) {
    int g = blockIdx.x * blockDim.x + threadIdx.x;
    if (g > NG) return;
    int lo = 0, hi = NN;
    while (lo < hi) {
        int mid = (lo + hi) >> 1;
        if (batch[mid] < g) lo = mid + 1; else hi = mid;
    }
    seg[g] = lo;
}

__global__ void k_lin0(const float* __restrict__ x, const float* __restrict__ w,
                       const float* __restrict__ b, float* __restrict__ h) {
    int lane = threadIdx.x & 63, wave = threadIdx.x >> 6;
    float Wc[15];
#pragma unroll
    for (int k = 0; k < 15; ++k) Wc[k] = w[k * DD + lane];
    float bias = b[lane];
    int n0 = blockIdx.x * 256;
    int n1 = min(n0 + 256, NN);
    for (int n = n0 + wave; n < n1; n += 4) {
        int nu = __builtin_amdgcn_readfirstlane(n);
        const float* xr = x + (size_t)nu * 15;
        float a = bias;
#pragma unroll
        for (int k = 0; k < 15; ++k) a += xr[k] * Wc[k];
        h[(size_t)nu * DD + lane] = fmaxf(a, 0.f);
    }
}

// Fused RGCN step, edge-parallel gather via LDS f32 atomics.
// Block: 512 thr (8 waves), 32 nodes, contiguous CSR edge range. 3125 blocks.
__global__ void __launch_bounds__(512) k_conv(
        const float* __restrict__ h, const int* __restrict__ eidx,
        const int* __restrict__ rowptr, const float* __restrict__ invc,
        const ushort_t* __restrict__ wt_hi, const ushort_t* __restrict__ wt_lo,
        const float* __restrict__ bias, float* __restrict__ hout) {
    __shared__ __align__(16) char smem[50176];
    float (*accf)[NR][64] = reinterpret_cast<float (*)[NR][64]>(smem);        // 40960 B
    ushort_t (*lhi)[392] = reinterpret_cast<ushort_t (*)[392]>(smem);         // 25088 B
    ushort_t (*llo)[392] = reinterpret_cast<ushort_t (*)[392]>(smem + 25088); // 25088 B

    int tid = threadIdx.x;
    int lane = tid & 63, w = tid >> 6;
    int n0 = blockIdx.x * 32;

    // zero accumulators
    for (int i = tid; i < 32 * NR * 64; i += 512) ((float*)smem)[i] = 0.f;
    __syncthreads();

    // ---- Phase A: edge-parallel gather (wave w takes every 8th edge) ----
    int e0 = rowptr[n0], e1 = rowptr[n0 + 32];
    for (int e = e0 + w; e < e1; e += 8) {
        int p = eidx[e];
        float v = h[(size_t)(p & 0xFFFFF) * DD + lane];
        atomicAdd(&accf[(p >> 23) & 31][(p >> 20) & 7][lane], v);
    }
    __syncthreads();

    // ---- Phase A2: read node sums into registers, scale ----
    float myv[4][6];
#pragma unroll
    for (int i = 0; i < 4; ++i) {
        int row = w * 4 + i;
        int n = n0 + row;
        float ic = invc[n];
#pragma unroll
        for (int t = 0; t < NR; ++t) myv[i][t] = accf[row][t][lane] * ic;
        myv[i][5] = h[(size_t)n * DD + lane];
    }
    __syncthreads();   // all accf reads done before overwrite

    // ---- Phase A3: bf16 split into staging tile (overwrites accf) ----
#pragma unroll
    for (int i = 0; i < 4; ++i) {
        int row = w * 4 + i;
#pragma unroll
        for (int t = 0; t < 6; ++t) {
            ushort_t hi = f2bf(myv[i][t]);
            ushort_t lo = f2bf(myv[i][t] - bf2f(hi));
            lhi[row][t * 64 + lane] = hi;
            llo[row][t * 64 + lane] = lo;
        }
    }
    __syncthreads();

    // ---- Phase B: split-bf16 MFMA from LDS ----
    int rg = w & 1;
    int ct = w >> 1;
    int crow = lane & 15, kb = lane >> 4;
    const ushort_t* pbh = wt_hi + (size_t)(ct * 16 + crow) * KK + kb * 8;
    const ushort_t* pbl = wt_lo + (size_t)(ct * 16 + crow) * KK + kb * 8;
    f32x4 acc = (f32x4){0.f, 0.f, 0.f, 0.f};
#pragma unroll 3
    for (int ks = 0; ks < 12; ++ks) {
        bf16x8 ahi = *(const bf16x8*)&lhi[rg * 16 + crow][ks * 32 + kb * 8];
        bf16x8 alo = *(const bf16x8*)&llo[rg * 16 + crow][ks * 32 + kb * 8];
        bf16x8 bhi = *(const bf16x8*)(pbh + ks * 32);
        bf16x8 blo = *(const bf16x8*)(pbl + ks * 32);
        acc = __builtin_amdgcn_mfma_f32_16x16x32_bf16(ahi, bhi, acc, 0, 0, 0);
        acc = __builtin_amdgcn_mfma_f32_16x16x32_bf16(ahi, blo, acc, 0, 0, 0);
        acc = __builtin_amdgcn_mfma_f32_16x16x32_bf16(alo, bhi, acc, 0, 0, 0);
    }
    float bv = bias[ct * 16 + crow];
#pragma unroll
    for (int r = 0; r < 4; ++r) {
        int n = n0 + rg * 16 + kb * 4 + r;
        hout[(size_t)n * DD + ct * 16 + crow] = fmaxf(acc[r] + bv, 0.f);
    }
}

// All 6 set2set steps, one block per graph; coalesced transposed weights.
__global__ void __launch_bounds__(256) k_s2s6(
        const float* __restrict__ h, const int* __restrict__ seg,
        const float* __restrict__ WqT, const float* __restrict__ WrT,
        const float* __restrict__ Wb, float* __restrict__ qstar) {
    int g = blockIdx.x;
    int tid = threadIdx.x;
    int lane = tid & 63, wave = tid >> 6;
    __shared__ float hsm[CAP][65];
    __shared__ float a_s[256];
    __shared__ float gates_s[256];
    __shared__ float hx_s[64], cx_s[64], r_s[64];
    __shared__ float red_s[4][64];
    __shared__ float m_s, sum_s;

    int s0 = seg[g], s1 = seg[g + 1];
    int len = min(s1 - s0, 256);
    int cap = min(len, CAP);
    for (int i = tid; i < cap * 64; i += 256) {
        int row = i >> 6, c = i & 63;
        hsm[row][c] = h[(size_t)(s0 + row) * DD + c];
    }
    if (tid < 64) { hx_s[tid] = 0.f; cx_s[tid] = 0.f; r_s[tid] = 0.f; }
    __syncthreads();

    for (int step = 0; step < 6; ++step) {
        // gates[j] = Wb[j] + sum_c hx[c]*WqT[c][j] + r[c]*WrT[c][j]  (coalesced in j)
        {
            float acc = Wb[tid];
#pragma unroll 8
            for (int c = 0; c < 64; ++c)
                acc += hx_s[c] * WqT[c * 256 + tid] + r_s[c] * WrT[c * 256 + tid];
            gates_s[tid] = acc;
        }
        __syncthreads();
        if (tid < 64) {
            float iv = sigmoidf_(gates_s[tid]);
            float fv = sigmoidf_(gates_s[64 + tid]);
            float gv = tanhf(gates_s[128 + tid]);
            float ov = sigmoidf_(gates_s[192 + tid]);
            float cc = fv * cx_s[tid] + iv * gv;
            cx_s[tid] = cc;
            hx_s[tid] = ov * tanhf(cc);
        }
        __syncthreads();

        // e[row] = hsm[row]·hx, thread per row
        for (int row = tid; row < len; row += 256) {
            const float* hr = (row < CAP) ? &hsm[row][0] : &h[(size_t)(s0 + row) * DD];
            float e = 0.f;
#pragma unroll 8
            for (int c = 0; c < 64; ++c) e += hr[c] * hx_s[c];
            a_s[row] = e;
        }
        __syncthreads();
        if (wave == 0) {
            float mm = -INFINITY;
            for (int row = lane; row < len; row += 64) mm = fmaxf(mm, a_s[row]);
#pragma unroll
            for (int off = 32; off >= 1; off >>= 1) mm = fmaxf(mm, __shfl_xor(mm, off, 64));
            if (lane == 0) m_s = mm;
        }
        __syncthreads();
        float m = m_s;
        for (int row = tid; row < len; row += 256) a_s[row] = expf(a_s[row] - m);
        __syncthreads();
        if (wave == 0) {
            float ss = 0.f;
            for (int row = lane; row < len; row += 64) ss += a_s[row];
#pragma unroll
            for (int off = 32; off >= 1; off >>= 1) ss += __shfl_xor(ss, off, 64);
            if (lane == 0) sum_s = ss;
        }
        __syncthreads();
        float racc = 0.f;
        for (int row = wave; row < len; row += 4) {
            const float* hr = (row < CAP) ? &hsm[row][0] : &h[(size_t)(s0 + row) * DD];
            racc += a_s[row] * hr[lane];
        }
        red_s[wave][lane] = racc;
        __syncthreads();
        if (tid < 64) {
            float r = red_s[0][tid] + red_s[1][tid] + red_s[2][tid] + red_s[3][tid];
            float s = sum_s;
            r_s[tid] = (s > 0.f) ? (r / s) : 0.f;
        }
        __syncthreads();
    }
    if (tid < 64) {
        qstar[(size_t)g * 2 * DD + tid] = hx_s[tid];
        qstar[(size_t)g * 2 * DD + DD + tid] = r_s[tid];
    }
}

// out = relu(q_star @ lin1 + b1) @ lin2 + b2
__global__ void k_final(const float* __restrict__ qstar, const float* __restrict__ w1,
                        const float* __restrict__ b1, const float* __restrict__ w2,
                        const float* __restrict__ b2, float* __restrict__ out) {
    int g = blockIdx.x;
    int j = threadIdx.x;
    float a = b1[j];
    const float* qs = qstar + (size_t)g * 2 * DD;
#pragma unroll 16
    for (int k = 0; k < 2 * DD; ++k) a += qs[k] * w1[k * DD + j];
    float t = fmaxf(a, 0.f);
    __shared__ float ts[64];
    ts[j] = t;
    __syncthreads();
    if (j < 12) {
        float o = b2[j];
#pragma unroll 16
        for (int d = 0; d < DD; ++d) o += ts[d] * w2[d * 12 + j];
        out[(size_t)g * 12 + j] = o;
    }
}

extern "C" void kernel_launch(void* const* d_in, const int* in_sizes, int n_in,
                              void* d_out, int out_size, void* d_ws, size_t ws_size,
                              hipStream_t stream) {
    const float* x     = (const float*)d_in[0];
    const int*   ei    = (const int*)d_in[1];
    const int*   etype = (const int*)d_in[2];
    const int*   batch = (const int*)d_in[3];
    const float* l0w   = (const float*)d_in[4];
    const float* l0b   = (const float*)d_in[5];
    const float* basis = (const float*)d_in[6];
    const float* att   = (const float*)d_in[7];
    const float* root  = (const float*)d_in[8];
    const float* convb = (const float*)d_in[9];
    const float* wih   = (const float*)d_in[10];
    const float* whh   = (const float*)d_in[11];
    const float* bih   = (const float*)d_in[12];
    const float* bhh   = (const float*)d_in[13];
    const float* l1w   = (const float*)d_in[14];
    const float* l1b   = (const float*)d_in[15];
    const float* l2w   = (const float*)d_in[16];
    const float* l2b   = (const float*)d_in[17];
    const int* src = ei;
    const int* dst = ei + NE;
    float* out = (float*)d_out;

    char* ws = (char*)d_ws;
    size_t off = 0;
    auto alloc = [&](size_t bytes) {
        void* p = ws + off;
        off = (off + bytes + 255) & ~(size_t)255;
        return p;
    };
    ushort_t* wt_hi = (ushort_t*)alloc((size_t)DD * KK * 2);
    ushort_t* wt_lo = (ushort_t*)alloc((size_t)DD * KK * 2);
    float* WqT    = (float*)alloc((size_t)64 * 256 * 4);
    float* WrT    = (float*)alloc((size_t)64 * 256 * 4);
    float* Wb     = (float*)alloc((size_t)256 * 4);
    float* h_a    = (float*)alloc((size_t)NN * DD * 4);
    float* h_b    = (float*)alloc((size_t)NN * DD * 4);
    int*   deg    = (int*)alloc((size_t)NN * 4);
    float* invc   = (float*)alloc((size_t)NN * 4);
    int*   part   = (int*)alloc((size_t)NN * 4);
    int*   bsum   = (int*)alloc((size_t)512 * 4);
    int*   rowptr = (int*)alloc((size_t)(NN + 1) * 4);
    int*   cur    = (int*)alloc((size_t)NN * 4);
    int*   eidx   = (int*)alloc((size_t)NE * 4);
    int*   seg    = (int*)alloc((size_t)(NG + 1) * 4);
    float* qstar  = (float*)alloc((size_t)NG * 2 * DD * 4);

    hipMemsetAsync(deg, 0, (size_t)NN * 4, stream);

    // CSR build
    k_cnt<<<(NE + 255) / 256, 256, 0, stream>>>(dst, deg);
    k_scan1<<<NB, 256, 0, stream>>>(deg, part, bsum);
    k_scan2<<<1, 512, 0, stream>>>(bsum);
    k_scan3<<<(NN + 255) / 256, 256, 0, stream>>>(part, bsum, deg, rowptr, invc);
    hipMemcpyAsync(cur, rowptr, (size_t)NN * 4, hipMemcpyDeviceToDevice, stream);
    k_fill<<<(NE + 255) / 256, 256, 0, stream>>>(src, dst, etype, cur, eidx);

    k_w2<<<(DD * KK + 255) / 256, 256, 0, stream>>>(att, basis, root, wt_hi, wt_lo);
    k_wf<<<(64 * 256 + 255) / 256, 256, 0, stream>>>(wih, whh, bih, bhh, WqT, WrT, Wb);
    k_seg<<<(NG + 256) / 256, 256, 0, stream>>>(batch, seg);
    k_lin0<<<(NN + 255) / 256, 256, 0, stream>>>(x, l0w, l0b, h_a);

    // 6 RGCN steps, ping-pong (even count: final state in h_a)
    for (int s = 0; s < 6; ++s) {
        const float* hin = (s & 1) ? h_b : h_a;
        float* hout      = (s & 1) ? h_a : h_b;
        k_conv<<<NN / 32, 512, 0, stream>>>(hin, eidx, rowptr, invc,
                                            wt_hi, wt_lo, convb, hout);
    }

    k_s2s6<<<NG, 256, 0, stream>>>(h_a, seg, WqT, WrT, Wb, qstar);

    k_final<<<NG, 64, 0, stream>>>(qstar, l1w, l1b, l2w, l2b, out);
}